// Round 1
// baseline (803.878 us; speedup 1.0000x reference)
//
#include <hip/hip_runtime.h>

// FP16 bit-pulse -> FP32 bit-pulse converter.
// Input : N x 16 floats, each exactly 0.0 or 1.0 (sign, e4..e0, m0..m9)
// Output: N x 32 floats (sign, 8 exp bits MSB-first, 23 mantissa bits)
// Exact integer-logic reduction of the reference gate network:
//   E==0  -> flush to signed zero (covers is_zero AND is_subnormal paths)
//   E==31 -> exp=0xFF, mantissa = M (inf has M==0, NaN keeps M)
//   else  -> exp=E+112, mantissa = M << 13
__global__ __launch_bounds__(256) void fp16_to_fp32_bits_kernel(
    const float* __restrict__ in, float* __restrict__ out, int n) {
    int tid = blockIdx.x * blockDim.x + threadIdx.x;
    int stride = gridDim.x * blockDim.x;
    for (int i = tid; i < n; i += stride) {
        const float4* ip = reinterpret_cast<const float4*>(in + (size_t)i * 16);
        float4 v0 = ip[0];
        float4 v1 = ip[1];
        float4 v2 = ip[2];
        float4 v3 = ip[3];
        float b[16] = {v0.x, v0.y, v0.z, v0.w, v1.x, v1.y, v1.z, v1.w,
                       v2.x, v2.y, v2.z, v2.w, v3.x, v3.y, v3.z, v3.w};

        // 5-bit exponent value, b[1] is MSB
        unsigned E = 0u;
#pragma unroll
        for (int k = 0; k < 5; ++k) E = (E << 1) | (b[1 + k] != 0.0f ? 1u : 0u);

        unsigned exp8 = (E == 31u) ? 255u : ((E == 0u) ? 0u : E + 112u);
        float msc = (E == 0u) ? 0.0f : 1.0f;

        float o[32];
        o[0] = b[0];  // sign copied verbatim
#pragma unroll
        for (int k = 0; k < 8; ++k) o[1 + k] = (float)((exp8 >> (7 - k)) & 1u);
#pragma unroll
        for (int j = 0; j < 10; ++j) o[9 + j] = b[6 + j] * msc;
#pragma unroll
        for (int j = 19; j < 32; ++j) o[j] = 0.0f;

        float4* op = reinterpret_cast<float4*>(out + (size_t)i * 32);
#pragma unroll
        for (int k = 0; k < 8; ++k)
            op[k] = make_float4(o[4 * k], o[4 * k + 1], o[4 * k + 2], o[4 * k + 3]);
    }
}

extern "C" void kernel_launch(void* const* d_in, const int* in_sizes, int n_in,
                              void* d_out, int out_size, void* d_ws, size_t ws_size,
                              hipStream_t stream) {
    const float* in = (const float*)d_in[0];
    float* out = (float*)d_out;
    int n = in_sizes[0] / 16;  // number of fp16 pulses
    int block = 256;
    int maxBlocks = 2048;  // 256 CUs x 8 blocks/CU; grid-stride the rest
    int blocks = (n + block - 1) / block;
    if (blocks > maxBlocks) blocks = maxBlocks;
    fp16_to_fp32_bits_kernel<<<blocks, block, 0, stream>>>(in, out, n);
}

// Round 3
// 676.356 us; speedup vs baseline: 1.1885x; 1.1885x over previous
//
#include <hip/hip_runtime.h>

// FP16 bit-pulse -> FP32 bit-pulse converter, lane-interleaved version.
//
// Task g (one per output float4): element e = g>>3, part p = g&7.
// Input float2 at flat index g belongs to the SAME element (e = g>>3,
// bit-pair q = g&7) -- so one flat index drives both the coalesced 8B load
// and the coalesced 16B store.
//
// The 8 lanes sharing an element exchange their 2-bit contributions with
// 3 shfl_xor ops; every lane then computes the element's full 32-bit output
// pattern with exact integer logic:
//   E==0  -> signed zero (covers reference's zero AND subnormal-flush paths)
//   E==31 -> exp=0xFF, mantissa = M (inf has M==0, NaN keeps M)
//   else  -> exp=E+112, mantissa = M << 13
__global__ __launch_bounds__(256) void fp16_to_fp32_bits_kernel(
    const uint2* __restrict__ in, float4* __restrict__ out, int n_tasks) {
    int tid = blockIdx.x * blockDim.x + threadIdx.x;
    int stride = gridDim.x * blockDim.x;
    for (int g = tid; g < n_tasks; g += stride) {
        uint2 u = in[g];                 // two input "bit" floats (0.0f or 1.0f)
        unsigned q = (unsigned)g & 7u;   // bit-pair index == output part index
        unsigned local = ((u.x ? 1u : 0u) | (u.y ? 2u : 0u)) << (2u * q);
        // OR-combine across the 8-lane element group (xor masks 1,2,4 stay in-group)
        local |= __shfl_xor((int)local, 1);
        local |= __shfl_xor((int)local, 2);
        local |= __shfl_xor((int)local, 4);
        // local: bit j = x[..., j] of this element (j=0 sign, 1..5 exp MSB->LSB, 6..15 mant)

        // 5-bit exponent value: numeric bit4 = x1 ... bit0 = x5 (bit-reverse of local>>1)
        unsigned E = __brev(local >> 1) >> 27;
        unsigned exp8 = (E == 31u) ? 255u : ((E == 0u) ? 0u : E + 112u);
        unsigned mmask = (E == 0u) ? 0u : 0x3FFu;

        // 32-bit output pattern: bit k = output float index k
        unsigned obits = (local & 1u)                      // sign
                       | ((__brev(exp8) >> 24) << 1)       // exp bits, MSB first at o[1..8]
                       | (((local >> 6) & mmask) << 9);    // mantissa at o[9..18]

        unsigned nib = (obits >> (4u * q)) & 0xFu;
        out[g] = make_float4((float)(nib & 1u), (float)((nib >> 1) & 1u),
                             (float)((nib >> 2) & 1u), (float)((nib >> 3) & 1u));
    }
}

extern "C" void kernel_launch(void* const* d_in, const int* in_sizes, int n_in,
                              void* d_out, int out_size, void* d_ws, size_t ws_size,
                              hipStream_t stream) {
    const uint2* in = (const uint2*)d_in[0];
    float4* out = (float4*)d_out;
    int n_tasks = in_sizes[0] / 2;  // one task per input float2 / output float4
    int block = 256;
    int maxBlocks = 2048;  // 256 CUs x 8 blocks/CU; grid-stride the rest
    int blocks = (n_tasks + block - 1) / block;
    if (blocks > maxBlocks) blocks = maxBlocks;
    fp16_to_fp32_bits_kernel<<<blocks, block, 0, stream>>>(in, out, n_tasks);
}